// Round 1
// baseline (2403.248 us; speedup 1.0000x reference)
//
#include <hip/hip_runtime.h>

#define SEQ 2048
#define NH 16
#define HD 64
#define DMODEL 1024

__device__ __forceinline__ unsigned int f2bf(float f) {
  // fp32 -> bf16 bits, round-to-nearest-even (finite inputs only)
  unsigned int u = __float_as_uint(f);
  return ((u + 0x7fffu + ((u >> 16) & 1u)) >> 16) & 0xffffu;
}

typedef __bf16 bf16x8 __attribute__((ext_vector_type(8)));
typedef float f32x4 __attribute__((ext_vector_type(4)));

__global__ __launch_bounds__(256) void cast_kernel(const float* __restrict__ in,
                                                   unsigned short* __restrict__ out,
                                                   int n8) {
  int idx = blockIdx.x * 256 + threadIdx.x;
  if (idx >= n8) return;
  const float4* p = reinterpret_cast<const float4*>(in) + (size_t)idx * 2;
  float4 a = p[0], b = p[1];
  uint4 o;
  o.x = f2bf(a.x) | (f2bf(a.y) << 16);
  o.y = f2bf(a.z) | (f2bf(a.w) << 16);
  o.z = f2bf(b.x) | (f2bf(b.y) << 16);
  o.w = f2bf(b.z) | (f2bf(b.w) << 16);
  reinterpret_cast<uint4*>(out)[idx] = o;
}

// C[m][n] = sum_k A[m][k]*B[n][k] + bias[n]
// A: [M][K] bf16 row-major, B: [N][K] bf16 row-major (i.e. B^T input), C: [M][N] fp32
__global__ __launch_bounds__(256) void gemm_bias_kernel(const unsigned short* __restrict__ A,
                                                        const unsigned short* __restrict__ B,
                                                        const float* __restrict__ bias,
                                                        float* __restrict__ C,
                                                        int M, int N, int K) {
  // 40 shorts = 80 B row pitch: 5*16B keeps every 8-element fragment 16B-aligned,
  // and the 20-bank shift/row breaks the power-of-2 conflict pattern.
  __shared__ unsigned short As[64][40];
  __shared__ unsigned short Bs[64][40];
  const int n0 = blockIdx.x * 64;
  const int m0 = blockIdx.y * 64;
  const int tid = threadIdx.x;
  const int wave = tid >> 6;
  const int lane = tid & 63;
  const int lr = tid >> 2;          // staging row 0..63
  const int lc = (tid & 3) * 8;     // staging col 0,8,16,24
  const int fr = lane & 15;         // fragment row within 16x16 tile
  const int fk = (lane >> 4) * 8;   // fragment k offset (verified m89/m91 layout)

  const unsigned short* Ag = A + (size_t)(m0 + lr) * K + lc;
  const unsigned short* Bg = B + (size_t)(n0 + lr) * K + lc;

  f32x4 acc0 = {0.f, 0.f, 0.f, 0.f};
  f32x4 acc1 = acc0, acc2 = acc0, acc3 = acc0;

  for (int k0 = 0; k0 < K; k0 += 32) {
    uint4 av = *reinterpret_cast<const uint4*>(Ag + k0);
    uint4 bv = *reinterpret_cast<const uint4*>(Bg + k0);
    *reinterpret_cast<uint4*>(&As[lr][lc]) = av;
    *reinterpret_cast<uint4*>(&Bs[lr][lc]) = bv;
    __syncthreads();
    bf16x8 af  = *reinterpret_cast<const bf16x8*>(&As[wave * 16 + fr][fk]);
    bf16x8 bf0 = *reinterpret_cast<const bf16x8*>(&Bs[fr][fk]);
    bf16x8 bf1 = *reinterpret_cast<const bf16x8*>(&Bs[16 + fr][fk]);
    bf16x8 bf2 = *reinterpret_cast<const bf16x8*>(&Bs[32 + fr][fk]);
    bf16x8 bf3 = *reinterpret_cast<const bf16x8*>(&Bs[48 + fr][fk]);
    acc0 = __builtin_amdgcn_mfma_f32_16x16x32_bf16(af, bf0, acc0, 0, 0, 0);
    acc1 = __builtin_amdgcn_mfma_f32_16x16x32_bf16(af, bf1, acc1, 0, 0, 0);
    acc2 = __builtin_amdgcn_mfma_f32_16x16x32_bf16(af, bf2, acc2, 0, 0, 0);
    acc3 = __builtin_amdgcn_mfma_f32_16x16x32_bf16(af, bf3, acc3, 0, 0, 0);
    __syncthreads();
  }
  // C/D layout: col = lane&15, row = (lane>>4)*4 + reg (m89/m91-verified)
  const int crow = m0 + wave * 16 + (lane >> 4) * 4;
  const int ccol0 = n0 + (lane & 15);
  f32x4 accs[4] = {acc0, acc1, acc2, acc3};
#pragma unroll
  for (int nt = 0; nt < 4; ++nt) {
    int col = ccol0 + nt * 16;
    float bsv = bias[col];
#pragma unroll
    for (int r = 0; r < 4; ++r) {
      C[(size_t)(crow + r) * N + col] = accs[nt][r] + bsv;
    }
  }
}

// fp32 flash attention, causal + pad mask.
// grid (32 i-blocks, 32 bh); block 256 = 4 waves; lane = query within 64-row tile.
// Each wave processes the interleaved j-chunks c == wave (mod 4) with private
// online-softmax state; states merged through LDS at the end.
__global__ __launch_bounds__(256, 2) void attn_kernel(const float* __restrict__ Q,
                                                      const float* __restrict__ Km,
                                                      const float* __restrict__ Vm,
                                                      const int* __restrict__ mask,
                                                      unsigned short* __restrict__ concat) {
  const int iblock = blockIdx.x;  // 0..31
  const int bh = blockIdx.y;      // 0..31
  const int b = bh >> 4;
  const int h = bh & 15;
  const int tid = threadIdx.x;
  const int wave = tid >> 6;
  const int lane = tid & 63;
  const int i = iblock * 64 + lane;

  __shared__ float sm_m[4][64];
  __shared__ float sm_l[4][64];
  __shared__ float sm_lstar[64];
  __shared__ float sm_acc[64][65];  // +1 pad: merge adds are 2-way bank aliased (free)

  for (int t = tid; t < 64 * 65; t += 256) (&sm_acc[0][0])[t] = 0.f;

  const int padi = mask[b * SEQ + i];
  const float* qrow = Q + ((size_t)(b * SEQ + i) * NH + h) * HD;
  float4 q[16];
#pragma unroll
  for (int d = 0; d < 16; ++d) q[d] = reinterpret_cast<const float4*>(qrow)[d];

  float4 acc[16];
#pragma unroll
  for (int d = 0; d < 16; ++d) acc[d] = make_float4(0.f, 0.f, 0.f, 0.f);
  float mrun = -1e30f, lrun = 0.f;

  const float* Kp = Km + ((size_t)b * SEQ * NH + h) * HD;
  const float* Vp = Vm + ((size_t)b * SEQ * NH + h) * HD;
  const int* maskb = mask + b * SEQ;

  for (int c = wave; c <= iblock; c += 4) {
    const int j0 = c * 64;
    for (int jj = 0; jj < 64; ++jj) {
      const int j = j0 + jj;
      const float4* kr = reinterpret_cast<const float4*>(Kp + (size_t)j * DMODEL);
      float s0 = 0.f, s1 = 0.f, s2 = 0.f, s3 = 0.f;  // 4 chains to cut dep latency
#pragma unroll
      for (int d = 0; d < 16; ++d) {
        float4 kv = kr[d];
        s0 = fmaf(q[d].x, kv.x, s0);
        s1 = fmaf(q[d].y, kv.y, s1);
        s2 = fmaf(q[d].z, kv.z, s2);
        s3 = fmaf(q[d].w, kv.w, s3);
      }
      float s = ((s0 + s1) + (s2 + s3)) * 0.125f;
      const bool valid = (j <= i) && (padi != 0) && (maskb[j] != 0);
      float mnew = valid ? fmaxf(mrun, s) : mrun;
      float p = valid ? __expf(s - mnew) : 0.f;   // p must be EXACTLY 0 when invalid
      float corr = __expf(mrun - mnew);           // ==1 when mnew==mrun
      lrun = lrun * corr + p;
      const float4* vr = reinterpret_cast<const float4*>(Vp + (size_t)j * DMODEL);
#pragma unroll
      for (int d = 0; d < 16; ++d) {
        float4 vv = vr[d];
        acc[d].x = fmaf(acc[d].x, corr, p * vv.x);
        acc[d].y = fmaf(acc[d].y, corr, p * vv.y);
        acc[d].z = fmaf(acc[d].z, corr, p * vv.z);
        acc[d].w = fmaf(acc[d].w, corr, p * vv.w);
      }
      mrun = mnew;
    }
  }

  sm_m[wave][lane] = mrun;
  sm_l[wave][lane] = lrun;
  __syncthreads();

  // merge 4 partial softmax states per query (all waves compute identically)
  float m0v = sm_m[0][lane], m1v = sm_m[1][lane], m2v = sm_m[2][lane], m3v = sm_m[3][lane];
  float msx = fmaxf(fmaxf(m0v, m1v), fmaxf(m2v, m3v));
  float f0 = __expf(m0v - msx), f1 = __expf(m1v - msx);
  float f2 = __expf(m2v - msx), f3 = __expf(m3v - msx);
  float ls = f0 * sm_l[0][lane] + f1 * sm_l[1][lane] + f2 * sm_l[2][lane] + f3 * sm_l[3][lane];
  if (wave == 0) sm_lstar[lane] = ls;
  float myf = (wave == 0) ? f0 : ((wave == 1) ? f1 : ((wave == 2) ? f2 : f3));

  // deterministic round-robin accumulate of scaled partials
  for (int w = 0; w < 4; ++w) {
    if (wave == w) {
#pragma unroll
      for (int d = 0; d < 16; ++d) {
        float* dst = &sm_acc[lane][d * 4];
        dst[0] += acc[d].x * myf;
        dst[1] += acc[d].y * myf;
        dst[2] += acc[d].z * myf;
        dst[3] += acc[d].w * myf;
      }
    }
    __syncthreads();
  }

  // write-out: thread -> (row qi, 16 cols starting at c0), bf16 packed 2x16B
  const int qi = tid >> 2;
  const int c0 = (tid & 3) * 16;
  float ls2 = sm_lstar[qi];
  float inv = (ls2 > 0.f) ? 1.f / ls2 : 0.f;  // fully-masked row -> zeros (matches ref)
  unsigned int w8[8];
#pragma unroll
  for (int p2 = 0; p2 < 8; ++p2) {
    float v0 = sm_acc[qi][c0 + p2 * 2] * inv;
    float v1 = sm_acc[qi][c0 + p2 * 2 + 1] * inv;
    w8[p2] = f2bf(v0) | (f2bf(v1) << 16);
  }
  unsigned short* orow =
      concat + ((size_t)(b * SEQ + iblock * 64 + qi) * NH + h) * HD + c0;
  reinterpret_cast<uint4*>(orow)[0] = make_uint4(w8[0], w8[1], w8[2], w8[3]);
  reinterpret_cast<uint4*>(orow)[1] = make_uint4(w8[4], w8[5], w8[6], w8[7]);
}

extern "C" void kernel_launch(void* const* d_in, const int* in_sizes, int n_in,
                              void* d_out, int out_size, void* d_ws, size_t ws_size,
                              hipStream_t stream) {
  (void)in_sizes; (void)n_in; (void)out_size;
  const float* x  = (const float*)d_in[0];
  const int* mask = (const int*)d_in[1];
  const float* Wq = (const float*)d_in[2];
  const float* bq = (const float*)d_in[3];
  const float* Wk = (const float*)d_in[4];
  const float* bk = (const float*)d_in[5];
  const float* Wv = (const float*)d_in[6];
  const float* bv = (const float*)d_in[7];
  const float* Wo = (const float*)d_in[8];
  const float* bo = (const float*)d_in[9];
  float* out = (float*)d_out;

  char* ws = (char*)d_ws;
  if (ws_size < (72ull << 20)) return;  // need 72 MB scratch
  unsigned short* xb  = (unsigned short*)(ws);                 // 8 MB: x bf16 [4096][1024]
  unsigned short* wqb = (unsigned short*)(ws + (8ull  << 20)); // 2 MB each
  unsigned short* wkb = (unsigned short*)(ws + (10ull << 20));
  unsigned short* wvb = (unsigned short*)(ws + (12ull << 20));
  unsigned short* wob = (unsigned short*)(ws + (14ull << 20));
  float* Qf = (float*)(ws + (16ull << 20));  // 16 MB each, [b,s,h,64] fp32
  float* Kf = (float*)(ws + (32ull << 20));
  float* Vf = (float*)(ws + (48ull << 20));
  unsigned short* cb = (unsigned short*)(ws + (64ull << 20));  // 8 MB concat bf16

  cast_kernel<<<2048, 256, 0, stream>>>(x, xb, 524288);
  cast_kernel<<<512, 256, 0, stream>>>(Wq, wqb, 131072);
  cast_kernel<<<512, 256, 0, stream>>>(Wk, wkb, 131072);
  cast_kernel<<<512, 256, 0, stream>>>(Wv, wvb, 131072);
  cast_kernel<<<512, 256, 0, stream>>>(Wo, wob, 131072);

  dim3 ggrid(16, 64);  // N/64, M/64
  gemm_bias_kernel<<<ggrid, 256, 0, stream>>>(xb, wqb, bq, Qf, 4096, 1024, 1024);
  gemm_bias_kernel<<<ggrid, 256, 0, stream>>>(xb, wkb, bk, Kf, 4096, 1024, 1024);
  gemm_bias_kernel<<<ggrid, 256, 0, stream>>>(xb, wvb, bv, Vf, 4096, 1024, 1024);

  attn_kernel<<<dim3(32, 32), 256, 0, stream>>>(Qf, Kf, Vf, mask, cb);

  gemm_bias_kernel<<<ggrid, 256, 0, stream>>>(cb, wob, bo, out, 4096, 1024, 1024);
}

// Round 2
// 290.258 us; speedup vs baseline: 8.2797x; 8.2797x over previous
//
#include <hip/hip_runtime.h>

#define SEQ 2048
#define NH 16
#define HD 64
#define DMODEL 1024

__device__ __forceinline__ unsigned int f2bf(float f) {
  // fp32 -> bf16 bits, round-to-nearest-even (finite inputs only)
  unsigned int u = __float_as_uint(f);
  return ((u + 0x7fffu + ((u >> 16) & 1u)) >> 16) & 0xffffu;
}

typedef __bf16 bf16x8 __attribute__((ext_vector_type(8)));
typedef float f32x4 __attribute__((ext_vector_type(4)));

__global__ __launch_bounds__(256) void cast_kernel(const float* __restrict__ in,
                                                   unsigned short* __restrict__ out,
                                                   int n8) {
  int idx = blockIdx.x * 256 + threadIdx.x;
  if (idx >= n8) return;
  const float4* p = reinterpret_cast<const float4*>(in) + (size_t)idx * 2;
  float4 a = p[0], b = p[1];
  uint4 o;
  o.x = f2bf(a.x) | (f2bf(a.y) << 16);
  o.y = f2bf(a.z) | (f2bf(a.w) << 16);
  o.z = f2bf(b.x) | (f2bf(b.y) << 16);
  o.w = f2bf(b.z) | (f2bf(b.w) << 16);
  reinterpret_cast<uint4*>(out)[idx] = o;
}

// C[m][n] = sum_k A[m][k]*B[n][k] + bias[n], with layout-templated epilogue.
// MODE 0: fp32 C[M][N]            (out projection)
// MODE 1: bf16 [b,h,s,64], value scaled by `scale` AFTER bias (Q with 0.125, K with 1)
// MODE 2: bf16 [b,h,64,s] (V transposed for attention B-operand)
template <int MODE>
__global__ __launch_bounds__(256) void gemm_epi_kernel(const unsigned short* __restrict__ A,
                                                       const unsigned short* __restrict__ B,
                                                       const float* __restrict__ bias,
                                                       float* __restrict__ Cf,
                                                       unsigned short* __restrict__ Cb,
                                                       int M, int N, int K, float scale) {
  __shared__ unsigned short As[64][40];
  __shared__ unsigned short Bs[64][40];
  const int n0 = blockIdx.x * 64;
  const int m0 = blockIdx.y * 64;
  const int tid = threadIdx.x;
  const int wave = tid >> 6;
  const int lane = tid & 63;
  const int lr = tid >> 2;
  const int lc = (tid & 3) * 8;
  const int fr = lane & 15;
  const int quad = lane >> 4;
  const int fk = quad * 8;

  const unsigned short* Ag = A + (size_t)(m0 + lr) * K + lc;
  const unsigned short* Bg = B + (size_t)(n0 + lr) * K + lc;

  f32x4 acc0 = {0.f, 0.f, 0.f, 0.f};
  f32x4 acc1 = acc0, acc2 = acc0, acc3 = acc0;

  for (int k0 = 0; k0 < K; k0 += 32) {
    uint4 av = *reinterpret_cast<const uint4*>(Ag + k0);
    uint4 bv = *reinterpret_cast<const uint4*>(Bg + k0);
    *reinterpret_cast<uint4*>(&As[lr][lc]) = av;
    *reinterpret_cast<uint4*>(&Bs[lr][lc]) = bv;
    __syncthreads();
    bf16x8 af  = *reinterpret_cast<const bf16x8*>(&As[wave * 16 + fr][fk]);
    bf16x8 bf0 = *reinterpret_cast<const bf16x8*>(&Bs[fr][fk]);
    bf16x8 bf1 = *reinterpret_cast<const bf16x8*>(&Bs[16 + fr][fk]);
    bf16x8 bf2 = *reinterpret_cast<const bf16x8*>(&Bs[32 + fr][fk]);
    bf16x8 bf3 = *reinterpret_cast<const bf16x8*>(&Bs[48 + fr][fk]);
    acc0 = __builtin_amdgcn_mfma_f32_16x16x32_bf16(af, bf0, acc0, 0, 0, 0);
    acc1 = __builtin_amdgcn_mfma_f32_16x16x32_bf16(af, bf1, acc1, 0, 0, 0);
    acc2 = __builtin_amdgcn_mfma_f32_16x16x32_bf16(af, bf2, acc2, 0, 0, 0);
    acc3 = __builtin_amdgcn_mfma_f32_16x16x32_bf16(af, bf3, acc3, 0, 0, 0);
    __syncthreads();
  }
  const int crow = m0 + wave * 16 + quad * 4;
  const int ccol0 = n0 + fr;
  f32x4 accs[4] = {acc0, acc1, acc2, acc3};
#pragma unroll
  for (int nt = 0; nt < 4; ++nt) {
    const int col = ccol0 + nt * 16;
    const float bsv = bias[col];
    if (MODE == 0) {
#pragma unroll
      for (int r = 0; r < 4; ++r)
        Cf[(size_t)(crow + r) * N + col] = accs[nt][r] + bsv;
    } else if (MODE == 1) {
      const int h = col >> 6, dv = col & 63, b = crow >> 11;
#pragma unroll
      for (int r = 0; r < 4; ++r) {
        const int s = (crow + r) & 2047;
        Cb[(((size_t)(b * NH + h)) * SEQ + s) * HD + dv] =
            (unsigned short)f2bf((accs[nt][r] + bsv) * scale);
      }
    } else {  // MODE 2: V^T [b,h,64,s]; rows r are contiguous in s -> 8B store
      const int h = col >> 6, dv = col & 63, b = crow >> 11, s0 = crow & 2047;
      ushort4 pk;
      pk.x = (unsigned short)f2bf(accs[nt][0] + bsv);
      pk.y = (unsigned short)f2bf(accs[nt][1] + bsv);
      pk.z = (unsigned short)f2bf(accs[nt][2] + bsv);
      pk.w = (unsigned short)f2bf(accs[nt][3] + bsv);
      *reinterpret_cast<ushort4*>(&Cb[(((size_t)(b * NH + h)) * HD + dv) * SEQ + s0]) = pk;
    }
  }
}

// MFMA flash attention, causal + pad mask. Block = 64 Q rows x one (b,h); 4 waves,
// wave owns Q rows [wave*16, wave*16+16). S^T = K*Q^T so lane's col (=lane&15) is its
// Q row -> per-lane online softmax state, row-reduce = 2 shuffles (xor 16, 32).
// P round-trips LDS (C-layout -> A-layout); V staged transposed [v][j] for B-frags.
__global__ __launch_bounds__(256) void attn_mfma_kernel(const unsigned short* __restrict__ Qg,
                                                        const unsigned short* __restrict__ Kg,
                                                        const unsigned short* __restrict__ Vtg,
                                                        const int* __restrict__ mask,
                                                        unsigned short* __restrict__ concat) {
  const int iblock = blockIdx.x;  // 0..31
  const int bh = blockIdx.y;      // 0..31
  const int b = bh >> 4;
  const int h = bh & 15;
  const int tid = threadIdx.x;
  const int wave = tid >> 6;
  const int lane = tid & 63;
  const int quad = lane >> 4;
  const int fr = lane & 15;
  const int i0 = iblock * 64;
  const int irow = i0 + wave * 16 + fr;  // this lane's Q row (softmax owner)

  // pitch 72 shorts = 144 B = 9*16B: fragment reads stay 16B-aligned, banks ~2-way
  __shared__ unsigned short Ks[64][72];
  __shared__ unsigned short Vts[64][72];
  __shared__ unsigned short Pt[4][16][72];

  const unsigned short* Qb = Qg + ((size_t)bh * SEQ) * HD;
  const unsigned short* Kb = Kg + ((size_t)bh * SEQ) * HD;
  const unsigned short* Vtb = Vtg + ((size_t)bh * HD) * SEQ;
  const int* maskb = mask + b * SEQ;

  const bf16x8 qf0 = *reinterpret_cast<const bf16x8*>(Qb + (size_t)irow * HD + quad * 8);
  const bf16x8 qf1 = *reinterpret_cast<const bf16x8*>(Qb + (size_t)irow * HD + quad * 8 + 32);
  const int padi = maskb[irow];

  f32x4 o[4];
#pragma unroll
  for (int vt = 0; vt < 4; ++vt) o[vt] = f32x4{0.f, 0.f, 0.f, 0.f};
  float mrun = -1e30f, lrun = 0.f;

  const int srow = tid >> 2;        // staging row 0..63
  const int spart = (tid & 3) * 2;  // uint4 part {0,2,4,6}

  for (int jc = 0; jc <= iblock; ++jc) {
    const int j0 = jc * 64;
    {  // stage K tile [j][k] and V^T tile [v][j]
      const uint4* kg = reinterpret_cast<const uint4*>(Kb + (size_t)(j0 + srow) * HD);
      const uint4* vg = reinterpret_cast<const uint4*>(Vtb + (size_t)srow * SEQ + j0);
      uint4 ka = kg[spart], kc = kg[spart + 1];
      uint4 va = vg[spart], vc = vg[spart + 1];
      *reinterpret_cast<uint4*>(&Ks[srow][spart * 8]) = ka;
      *reinterpret_cast<uint4*>(&Ks[srow][spart * 8 + 8]) = kc;
      *reinterpret_cast<uint4*>(&Vts[srow][spart * 8]) = va;
      *reinterpret_cast<uint4*>(&Vts[srow][spart * 8 + 8]) = vc;
    }
    __syncthreads();

    // S^T strip: C[m=j (quad*4+reg within jt)][n=i (fr)]
    f32x4 st[4];
#pragma unroll
    for (int jt = 0; jt < 4; ++jt) {
      st[jt] = f32x4{0.f, 0.f, 0.f, 0.f};
      bf16x8 ka0 = *reinterpret_cast<const bf16x8*>(&Ks[jt * 16 + fr][quad * 8]);
      bf16x8 ka1 = *reinterpret_cast<const bf16x8*>(&Ks[jt * 16 + fr][quad * 8 + 32]);
      st[jt] = __builtin_amdgcn_mfma_f32_16x16x32_bf16(ka0, qf0, st[jt], 0, 0, 0);
      st[jt] = __builtin_amdgcn_mfma_f32_16x16x32_bf16(ka1, qf1, st[jt], 0, 0, 0);
    }

    // mask: pad(j) always; causal only on diagonal tile
    const bool diag = (jc == iblock);
    const int4* mp = reinterpret_cast<const int4*>(maskb + j0);
#pragma unroll
    for (int jt = 0; jt < 4; ++jt) {
      const int4 mv = mp[jt * 4 + quad];
      const int jb = j0 + jt * 16 + quad * 4;
      if (mv.x == 0 || (diag && jb + 0 > irow)) st[jt][0] = -1e30f;
      if (mv.y == 0 || (diag && jb + 1 > irow)) st[jt][1] = -1e30f;
      if (mv.z == 0 || (diag && jb + 2 > irow)) st[jt][2] = -1e30f;
      if (mv.w == 0 || (diag && jb + 3 > irow)) st[jt][3] = -1e30f;
    }

    // online softmax for row fr (state replicated across the 4 quads)
    float tmax = -1e30f;
#pragma unroll
    for (int jt = 0; jt < 4; ++jt)
#pragma unroll
      for (int r = 0; r < 4; ++r) tmax = fmaxf(tmax, st[jt][r]);
    tmax = fmaxf(tmax, __shfl_xor(tmax, 16));
    tmax = fmaxf(tmax, __shfl_xor(tmax, 32));
    const float mnew = fmaxf(mrun, tmax);
    const float corr = __expf(mrun - mnew);
    float p[16];
    float lloc = 0.f;
#pragma unroll
    for (int jt = 0; jt < 4; ++jt)
#pragma unroll
      for (int r = 0; r < 4; ++r) {
        float pv = __expf(st[jt][r] - mnew);
        p[jt * 4 + r] = pv;
        lloc += pv;
      }
    lloc += __shfl_xor(lloc, 16);
    lloc += __shfl_xor(lloc, 32);
    lrun = lrun * corr + lloc;
    mrun = mnew;

    // P (bf16) -> per-wave LDS strip [i=fr][j], one b64 write per jt
#pragma unroll
    for (int jt = 0; jt < 4; ++jt) {
      ushort4 pk;
      pk.x = (unsigned short)f2bf(p[jt * 4 + 0]);
      pk.y = (unsigned short)f2bf(p[jt * 4 + 1]);
      pk.z = (unsigned short)f2bf(p[jt * 4 + 2]);
      pk.w = (unsigned short)f2bf(p[jt * 4 + 3]);
      *reinterpret_cast<ushort4*>(&Pt[wave][fr][jt * 16 + quad * 4]) = pk;
    }

    // rescale O rows (O C-layout rows = quad*4+r; corr lives at lane fr==row)
    const float c0 = __shfl(corr, quad * 4 + 0);
    const float c1 = __shfl(corr, quad * 4 + 1);
    const float c2 = __shfl(corr, quad * 4 + 2);
    const float c3 = __shfl(corr, quad * 4 + 3);
#pragma unroll
    for (int vt = 0; vt < 4; ++vt) {
      o[vt][0] *= c0; o[vt][1] *= c1; o[vt][2] *= c2; o[vt][3] *= c3;
    }

    // O += P*V : A=P from Pt (A-layout), B=V^T rows from Vts
    bf16x8 pa0 = *reinterpret_cast<const bf16x8*>(&Pt[wave][fr][quad * 8]);
    bf16x8 pa1 = *reinterpret_cast<const bf16x8*>(&Pt[wave][fr][quad * 8 + 32]);
#pragma unroll
    for (int vt = 0; vt < 4; ++vt) {
      bf16x8 vb0 = *reinterpret_cast<const bf16x8*>(&Vts[vt * 16 + fr][quad * 8]);
      bf16x8 vb1 = *reinterpret_cast<const bf16x8*>(&Vts[vt * 16 + fr][quad * 8 + 32]);
      o[vt] = __builtin_amdgcn_mfma_f32_16x16x32_bf16(pa0, vb0, o[vt], 0, 0, 0);
      o[vt] = __builtin_amdgcn_mfma_f32_16x16x32_bf16(pa1, vb1, o[vt], 0, 0, 0);
    }
    __syncthreads();  // protect Ks/Vts before next stage
  }

  // epilogue: O[i=quad*4+r][v=vt*16+fr] / l_i -> concat bf16 [b,s,h*64]
#pragma unroll
  for (int r = 0; r < 4; ++r) {
    const float lr = __shfl(lrun, quad * 4 + r);
    const int pr = __shfl(padi, quad * 4 + r);
    const float inv = (pr != 0 && lr > 0.f) ? 1.f / lr : 0.f;
    const int iout = i0 + wave * 16 + quad * 4 + r;
    unsigned short* orow = concat + ((size_t)(b * SEQ + iout)) * DMODEL + h * HD + fr;
    orow[0]  = (unsigned short)f2bf(o[0][r] * inv);
    orow[16] = (unsigned short)f2bf(o[1][r] * inv);
    orow[32] = (unsigned short)f2bf(o[2][r] * inv);
    orow[48] = (unsigned short)f2bf(o[3][r] * inv);
  }
}

extern "C" void kernel_launch(void* const* d_in, const int* in_sizes, int n_in,
                              void* d_out, int out_size, void* d_ws, size_t ws_size,
                              hipStream_t stream) {
  (void)in_sizes; (void)n_in; (void)out_size;
  const float* x  = (const float*)d_in[0];
  const int* mask = (const int*)d_in[1];
  const float* Wq = (const float*)d_in[2];
  const float* bq = (const float*)d_in[3];
  const float* Wk = (const float*)d_in[4];
  const float* bk = (const float*)d_in[5];
  const float* Wv = (const float*)d_in[6];
  const float* bv = (const float*)d_in[7];
  const float* Wo = (const float*)d_in[8];
  const float* bo = (const float*)d_in[9];
  float* out = (float*)d_out;

  char* ws = (char*)d_ws;
  if (ws_size < (48ull << 20)) return;
  unsigned short* xb  = (unsigned short*)(ws);                 // 8 MB x bf16 [4096][1024]
  unsigned short* wqb = (unsigned short*)(ws + (8ull  << 20)); // 2 MB each
  unsigned short* wkb = (unsigned short*)(ws + (10ull << 20));
  unsigned short* wvb = (unsigned short*)(ws + (12ull << 20));
  unsigned short* wob = (unsigned short*)(ws + (14ull << 20));
  unsigned short* Qb  = (unsigned short*)(ws + (16ull << 20)); // 8 MB [b,h,s,64] (x0.125)
  unsigned short* Kb  = (unsigned short*)(ws + (24ull << 20)); // 8 MB [b,h,s,64]
  unsigned short* Vtb = (unsigned short*)(ws + (32ull << 20)); // 8 MB [b,h,64,s]
  unsigned short* cb  = (unsigned short*)(ws + (40ull << 20)); // 8 MB concat bf16

  cast_kernel<<<2048, 256, 0, stream>>>(x, xb, 524288);
  cast_kernel<<<512, 256, 0, stream>>>(Wq, wqb, 131072);
  cast_kernel<<<512, 256, 0, stream>>>(Wk, wkb, 131072);
  cast_kernel<<<512, 256, 0, stream>>>(Wv, wvb, 131072);
  cast_kernel<<<512, 256, 0, stream>>>(Wo, wob, 131072);

  dim3 ggrid(16, 64);  // N/64, M/64
  gemm_epi_kernel<1><<<ggrid, 256, 0, stream>>>(xb, wqb, bq, nullptr, Qb, 4096, 1024, 1024, 0.125f);
  gemm_epi_kernel<1><<<ggrid, 256, 0, stream>>>(xb, wkb, bk, nullptr, Kb, 4096, 1024, 1024, 1.0f);
  gemm_epi_kernel<2><<<ggrid, 256, 0, stream>>>(xb, wvb, bv, nullptr, Vtb, 4096, 1024, 1024, 1.0f);

  attn_mfma_kernel<<<dim3(32, 32), 256, 0, stream>>>(Qb, Kb, Vtb, mask, cb);

  gemm_epi_kernel<0><<<ggrid, 256, 0, stream>>>(cb, wob, bo, out, nullptr, 4096, 1024, 1024, 1.0f);
}

// Round 3
// 219.765 us; speedup vs baseline: 10.9355x; 1.3208x over previous
//
#include <hip/hip_runtime.h>

#define SEQ 2048
#define NH 16
#define HD 64
#define DMODEL 1024

__device__ __forceinline__ unsigned int f2bf(float f) {
  // fp32 -> bf16 bits, round-to-nearest-even (finite inputs only)
  unsigned int u = __float_as_uint(f);
  return ((u + 0x7fffu + ((u >> 16) & 1u)) >> 16) & 0xffffu;
}

typedef __bf16 bf16x8 __attribute__((ext_vector_type(8)));
typedef float f32x4 __attribute__((ext_vector_type(4)));

// async global->LDS, 16B per lane; LDS dest = wave-uniform base + lane*16
__device__ __forceinline__ void gl2lds16(const unsigned short* g, unsigned short* l) {
  __builtin_amdgcn_global_load_lds(
      (const __attribute__((address_space(1))) unsigned int*)g,
      (__attribute__((address_space(3))) unsigned int*)l, 16, 0, 0);
}

// one launch casts x + all four weight matrices to bf16
__global__ __launch_bounds__(256) void cast_all_kernel(
    const float* __restrict__ x, const float* __restrict__ wq,
    const float* __restrict__ wk, const float* __restrict__ wv,
    const float* __restrict__ wo,
    unsigned short* __restrict__ xb, unsigned short* __restrict__ wqb,
    unsigned short* __restrict__ wkb, unsigned short* __restrict__ wvb,
    unsigned short* __restrict__ wob) {
  int idx = blockIdx.x * 256 + threadIdx.x;
  if (idx >= 1048576) return;
  const float* src;
  unsigned short* dst;
  int off;
  if (idx < 524288) {
    src = x; dst = xb; off = idx;
  } else {
    int t = idx - 524288;
    int w = t >> 17;
    off = t & 131071;
    src = (w == 0) ? wq : (w == 1) ? wk : (w == 2) ? wv : wo;
    dst = (w == 0) ? wqb : (w == 1) ? wkb : (w == 2) ? wvb : wob;
  }
  const float4* p = reinterpret_cast<const float4*>(src) + (size_t)off * 2;
  float4 a = p[0], b = p[1];
  uint4 o;
  o.x = f2bf(a.x) | (f2bf(a.y) << 16);
  o.y = f2bf(a.z) | (f2bf(a.w) << 16);
  o.z = f2bf(b.x) | (f2bf(b.y) << 16);
  o.w = f2bf(b.z) | (f2bf(b.w) << 16);
  reinterpret_cast<uint4*>(dst)[off] = o;
}

// 128x128-tile GEMM, BK=64, global_load_lds staging (m97 structure).
// C[m][n] = sum_k A[m][k]*B[n][k] (+bias), A [M][K] bf16, B [N][K] bf16.
// MODE 0: fused QKV epilogue. Columns 0..1023 -> Q ([b,h,s,64], *0.125 after bias),
//         1024..2047 -> K ([b,h,s,64]), 2048..3071 -> V^T ([b,h,64,s]). bf16 out.
// MODE 1: fp32 C[M][1024] + bias0 (out projection).
template <int MODE>
__global__ __launch_bounds__(256) void gemm128(
    const unsigned short* __restrict__ A, const unsigned short* __restrict__ B,
    const float* __restrict__ bias0, const float* __restrict__ bias1,
    const float* __restrict__ bias2, float* __restrict__ Cf,
    unsigned short* __restrict__ Qo, unsigned short* __restrict__ Ko,
    unsigned short* __restrict__ Vto, int Kdim) {
  __shared__ __align__(16) unsigned short As[128 * 64];
  __shared__ __align__(16) unsigned short Bs[128 * 64];
  const int tid = threadIdx.x;
  const int wave = tid >> 6, lane = tid & 63;
  const int wm = wave >> 1, wn = wave & 1;  // 2x2 waves -> 64x64 sub-tiles
  const int fr = lane & 15, quad = lane >> 4;
  const int n0 = blockIdx.x * 128, m0 = blockIdx.y * 128;

  // staging: wave stages A rows [wave*32, wave*32+32) (and B likewise) in 4 loads
  // of 8 rows; lane -> (row = lane>>3, 16B chunk = lane&7). No LDS padding
  // (global_load_lds dest is base + lane*16).
  const unsigned short* Abase =
      A + (size_t)(m0 + wave * 32 + (lane >> 3)) * Kdim + (lane & 7) * 8;
  const unsigned short* Bbase =
      B + (size_t)(n0 + wave * 32 + (lane >> 3)) * Kdim + (lane & 7) * 8;
  unsigned short* AsW = As + (wave * 32) * 64;
  unsigned short* BsW = Bs + (wave * 32) * 64;

  f32x4 acc[4][4];
#pragma unroll
  for (int mt = 0; mt < 4; ++mt)
#pragma unroll
    for (int nt = 0; nt < 4; ++nt) acc[mt][nt] = f32x4{0.f, 0.f, 0.f, 0.f};

  for (int k0 = 0; k0 < Kdim; k0 += 64) {
#pragma unroll
    for (int t = 0; t < 4; ++t) {
      gl2lds16(Abase + (size_t)(t * 8) * Kdim + k0, AsW + t * 8 * 64);
      gl2lds16(Bbase + (size_t)(t * 8) * Kdim + k0, BsW + t * 8 * 64);
    }
    __syncthreads();  // drains vmcnt(0): staged tile visible
#pragma unroll
    for (int ks = 0; ks < 2; ++ks) {
      bf16x8 af[4], bfv[4];
#pragma unroll
      for (int mt = 0; mt < 4; ++mt)
        af[mt] = *reinterpret_cast<const bf16x8*>(
            As + (wm * 64 + mt * 16 + fr) * 64 + ks * 32 + quad * 8);
#pragma unroll
      for (int nt = 0; nt < 4; ++nt)
        bfv[nt] = *reinterpret_cast<const bf16x8*>(
            Bs + (wn * 64 + nt * 16 + fr) * 64 + ks * 32 + quad * 8);
#pragma unroll
      for (int mt = 0; mt < 4; ++mt)
#pragma unroll
        for (int nt = 0; nt < 4; ++nt)
          acc[mt][nt] = __builtin_amdgcn_mfma_f32_16x16x32_bf16(
              af[mt], bfv[nt], acc[mt][nt], 0, 0, 0);
    }
    __syncthreads();
  }

  // epilogue. C/D: col = lane&15, row = quad*4+reg (m89/m91-verified).
  if (MODE == 0) {
    const int seg = n0 >> 10;  // uniform per block (128 | 1024)
    const float* bp = (seg == 0) ? bias0 : (seg == 1) ? bias1 : bias2;
    const float scale = (seg == 0) ? 0.125f : 1.0f;
    unsigned short* QK = (seg == 0) ? Qo : Ko;
#pragma unroll
    for (int nt = 0; nt < 4; ++nt) {
      const int c = (n0 + wn * 64 + nt * 16 + fr) & 1023;
      const int h = c >> 6, d = c & 63;
      const float bs = bp[c];
#pragma unroll
      for (int mt = 0; mt < 4; ++mt) {
        const int mbase = m0 + wm * 64 + mt * 16 + quad * 4;
        const int b = mbase >> 11, s0 = mbase & 2047;
        if (seg < 2) {
          unsigned short* dst = QK + (((size_t)(b * NH + h)) * SEQ + s0) * HD + d;
#pragma unroll
          for (int r = 0; r < 4; ++r)
            dst[(size_t)r * HD] = (unsigned short)f2bf((acc[mt][nt][r] + bs) * scale);
        } else {  // V^T: rows contiguous in s -> ushort4
          ushort4 pk;
          pk.x = (unsigned short)f2bf(acc[mt][nt][0] + bs);
          pk.y = (unsigned short)f2bf(acc[mt][nt][1] + bs);
          pk.z = (unsigned short)f2bf(acc[mt][nt][2] + bs);
          pk.w = (unsigned short)f2bf(acc[mt][nt][3] + bs);
          *reinterpret_cast<ushort4*>(
              Vto + (((size_t)(b * NH + h)) * HD + d) * SEQ + s0) = pk;
        }
      }
    }
  } else {
#pragma unroll
    for (int nt = 0; nt < 4; ++nt) {
      const int cg = n0 + wn * 64 + nt * 16 + fr;
      const float bs = bias0[cg];
#pragma unroll
      for (int mt = 0; mt < 4; ++mt) {
        const int mbase = m0 + wm * 64 + mt * 16 + quad * 4;
#pragma unroll
        for (int r = 0; r < 4; ++r)
          Cf[(size_t)(mbase + r) * DMODEL + cg] = acc[mt][nt][r] + bs;
      }
    }
  }
}

// MFMA flash attention. S^T = K*Q^T (lane col = its Q row i), then O^T = V^T*P^T
// so lane col stays i: softmax state, corr rescale, and epilogue all shuffle-free
// except the 2+2 xor reductions. Flat grid, heavy iblocks dispatched first.
__global__ __launch_bounds__(256) void attn_mfma_kernel(const unsigned short* __restrict__ Qg,
                                                        const unsigned short* __restrict__ Kg,
                                                        const unsigned short* __restrict__ Vtg,
                                                        const int* __restrict__ mask,
                                                        unsigned short* __restrict__ concat) {
  const int iblock = 31 - (blockIdx.x >> 5);  // heavy blocks first
  const int bh = blockIdx.x & 31;
  const int b = bh >> 4;
  const int h = bh & 15;
  const int tid = threadIdx.x;
  const int wave = tid >> 6;
  const int lane = tid & 63;
  const int quad = lane >> 4;
  const int fr = lane & 15;
  const int i0 = iblock * 64;
  const int irow = i0 + wave * 16 + fr;  // this lane's Q row (softmax owner)

  __shared__ unsigned short Ks[64][72];   // pitch 72 shorts = 144 B (16B-aligned frags)
  __shared__ unsigned short Vts[64][72];
  __shared__ unsigned short Pt[4][16][72];

  const unsigned short* Qb = Qg + ((size_t)bh * SEQ) * HD;
  const unsigned short* Kb = Kg + ((size_t)bh * SEQ) * HD;
  const unsigned short* Vtb = Vtg + ((size_t)bh * HD) * SEQ;
  const int* maskb = mask + b * SEQ;

  const bf16x8 qf0 = *reinterpret_cast<const bf16x8*>(Qb + (size_t)irow * HD + quad * 8);
  const bf16x8 qf1 = *reinterpret_cast<const bf16x8*>(Qb + (size_t)irow * HD + quad * 8 + 32);
  const int padi = maskb[irow];

  f32x4 o[4];
#pragma unroll
  for (int vt = 0; vt < 4; ++vt) o[vt] = f32x4{0.f, 0.f, 0.f, 0.f};
  float mrun = -1e30f, lrun = 0.f;

  const int srow = tid >> 2;        // staging row 0..63
  const int spart = (tid & 3) * 2;  // uint4 part {0,2,4,6}

  for (int jc = 0; jc <= iblock; ++jc) {
    const int j0 = jc * 64;
    {  // stage K tile [j][k] and V^T tile [v][j]
      const uint4* kg = reinterpret_cast<const uint4*>(Kb + (size_t)(j0 + srow) * HD);
      const uint4* vg = reinterpret_cast<const uint4*>(Vtb + (size_t)srow * SEQ + j0);
      uint4 ka = kg[spart], kc = kg[spart + 1];
      uint4 va = vg[spart], vc = vg[spart + 1];
      *reinterpret_cast<uint4*>(&Ks[srow][spart * 8]) = ka;
      *reinterpret_cast<uint4*>(&Ks[srow][spart * 8 + 8]) = kc;
      *reinterpret_cast<uint4*>(&Vts[srow][spart * 8]) = va;
      *reinterpret_cast<uint4*>(&Vts[srow][spart * 8 + 8]) = vc;
    }
    __syncthreads();

    // S^T strip: C[m=j][n=i=fr]
    f32x4 st[4];
#pragma unroll
    for (int jt = 0; jt < 4; ++jt) {
      st[jt] = f32x4{0.f, 0.f, 0.f, 0.f};
      bf16x8 ka0 = *reinterpret_cast<const bf16x8*>(&Ks[jt * 16 + fr][quad * 8]);
      bf16x8 ka1 = *reinterpret_cast<const bf16x8*>(&Ks[jt * 16 + fr][quad * 8 + 32]);
      st[jt] = __builtin_amdgcn_mfma_f32_16x16x32_bf16(ka0, qf0, st[jt], 0, 0, 0);
      st[jt] = __builtin_amdgcn_mfma_f32_16x16x32_bf16(ka1, qf1, st[jt], 0, 0, 0);
    }

    // mask: pad(j) always; causal only on diagonal tile
    const bool diag = (jc == iblock);
    const int4* mp = reinterpret_cast<const int4*>(maskb + j0);
#pragma unroll
    for (int jt = 0; jt < 4; ++jt) {
      const int4 mv = mp[jt * 4 + quad];
      const int jb = j0 + jt * 16 + quad * 4;
      if (mv.x == 0 || (diag && jb + 0 > irow)) st[jt][0] = -1e30f;
      if (mv.y == 0 || (diag && jb + 1 > irow)) st[jt][1] = -1e30f;
      if (mv.z == 0 || (diag && jb + 2 > irow)) st[jt][2] = -1e30f;
      if (mv.w == 0 || (diag && jb + 3 > irow)) st[jt][3] = -1e30f;
    }

    // online softmax for row i=fr (state replicated across the 4 quads)
    float tmax = -1e30f;
#pragma unroll
    for (int jt = 0; jt < 4; ++jt)
#pragma unroll
      for (int r = 0; r < 4; ++r) tmax = fmaxf(tmax, st[jt][r]);
    tmax = fmaxf(tmax, __shfl_xor(tmax, 16));
    tmax = fmaxf(tmax, __shfl_xor(tmax, 32));
    float mnew = fmaxf(fmaxf(mrun, tmax), -1e20f);  // clamp: all-masked tile -> p=0
    const float corr = __expf(mrun - mnew);
    float p[16];
    float lloc = 0.f;
#pragma unroll
    for (int jt = 0; jt < 4; ++jt)
#pragma unroll
      for (int r = 0; r < 4; ++r) {
        float pv = __expf(st[jt][r] - mnew);
        p[jt * 4 + r] = pv;
        lloc += pv;
      }
    lloc += __shfl_xor(lloc, 16);
    lloc += __shfl_xor(lloc, 32);
    lrun = lrun * corr + lloc;
    mrun = mnew;

    // P (bf16) -> per-wave LDS strip [i][j]
#pragma unroll
    for (int jt = 0; jt < 4; ++jt) {
      ushort4 pk;
      pk.x = (unsigned short)f2bf(p[jt * 4 + 0]);
      pk.y = (unsigned short)f2bf(p[jt * 4 + 1]);
      pk.z = (unsigned short)f2bf(p[jt * 4 + 2]);
      pk.w = (unsigned short)f2bf(p[jt * 4 + 3]);
      *reinterpret_cast<ushort4*>(&Pt[wave][fr][jt * 16 + quad * 4]) = pk;
    }

    // O^T rescale: lane's col is its own Q row -> no shuffles
#pragma unroll
    for (int vt = 0; vt < 4; ++vt) {
      o[vt][0] *= corr; o[vt][1] *= corr; o[vt][2] *= corr; o[vt][3] *= corr;
    }

    // O^T += V^T * P^T : A-frag = V^T rows, B-frag = P^T cols (same LDS reads as P rows)
    bf16x8 pa0 = *reinterpret_cast<const bf16x8*>(&Pt[wave][fr][quad * 8]);
    bf16x8 pa1 = *reinterpret_cast<const bf16x8*>(&Pt[wave][fr][quad * 8 + 32]);
#pragma unroll
    for (int vt = 0; vt < 4; ++vt) {
      bf16x8 vb0 = *reinterpret_cast<const bf16x8*>(&Vts[vt * 16 + fr][quad * 8]);
      bf16x8 vb1 = *reinterpret_cast<const bf16x8*>(&Vts[vt * 16 + fr][quad * 8 + 32]);
      o[vt] = __builtin_amdgcn_mfma_f32_16x16x32_bf16(vb0, pa0, o[vt], 0, 0, 0);
      o[vt] = __builtin_amdgcn_mfma_f32_16x16x32_bf16(vb1, pa1, o[vt], 0, 0, 0);
    }
    __syncthreads();  // protect Ks/Vts before next stage
  }

  // epilogue: O^T[v=vt*16+quad*4+r][i=fr] / l_i -> concat bf16 [b,s,h*64]
  const float inv = (padi != 0 && lrun > 0.f) ? 1.f / lrun : 0.f;
  unsigned short* orow = concat + ((size_t)(b * SEQ + irow)) * DMODEL + h * HD;
#pragma unroll
  for (int vt = 0; vt < 4; ++vt) {
    ushort4 pk;
    pk.x = (unsigned short)f2bf(o[vt][0] * inv);
    pk.y = (unsigned short)f2bf(o[vt][1] * inv);
    pk.z = (unsigned short)f2bf(o[vt][2] * inv);
    pk.w = (unsigned short)f2bf(o[vt][3] * inv);
    *reinterpret_cast<ushort4*>(orow + vt * 16 + quad * 4) = pk;
  }
}

extern "C" void kernel_launch(void* const* d_in, const int* in_sizes, int n_in,
                              void* d_out, int out_size, void* d_ws, size_t ws_size,
                              hipStream_t stream) {
  (void)in_sizes; (void)n_in; (void)out_size;
  const float* x  = (const float*)d_in[0];
  const int* mask = (const int*)d_in[1];
  const float* Wq = (const float*)d_in[2];
  const float* bq = (const float*)d_in[3];
  const float* Wk = (const float*)d_in[4];
  const float* bk = (const float*)d_in[5];
  const float* Wv = (const float*)d_in[6];
  const float* bv = (const float*)d_in[7];
  const float* Wo = (const float*)d_in[8];
  const float* bo = (const float*)d_in[9];
  float* out = (float*)d_out;

  char* ws = (char*)d_ws;
  if (ws_size < (48ull << 20)) return;
  unsigned short* xb  = (unsigned short*)(ws);                 // 8 MB x bf16 [4096][1024]
  unsigned short* wqb = (unsigned short*)(ws + (8ull  << 20)); // wq|wk|wv contiguous ->
  unsigned short* wkb = (unsigned short*)(ws + (10ull << 20)); //   [3072][1024] B matrix
  unsigned short* wvb = (unsigned short*)(ws + (12ull << 20));
  unsigned short* wob = (unsigned short*)(ws + (14ull << 20));
  unsigned short* Qb  = (unsigned short*)(ws + (16ull << 20)); // 8 MB [b,h,s,64] (x0.125)
  unsigned short* Kb  = (unsigned short*)(ws + (24ull << 20)); // 8 MB [b,h,s,64]
  unsigned short* Vtb = (unsigned short*)(ws + (32ull << 20)); // 8 MB [b,h,64,s]
  unsigned short* cb  = (unsigned short*)(ws + (40ull << 20)); // 8 MB concat bf16

  cast_all_kernel<<<4096, 256, 0, stream>>>(x, Wq, Wk, Wv, Wo, xb, wqb, wkb, wvb, wob);

  // fused QKV projection: B = [wq; wk; wv] = [3072][1024]
  gemm128<0><<<dim3(24, 32), 256, 0, stream>>>(xb, wqb, bq, bk, bv,
                                               nullptr, Qb, Kb, Vtb, 1024);

  attn_mfma_kernel<<<1024, 256, 0, stream>>>(Qb, Kb, Vtb, mask, cb);

  gemm128<1><<<dim3(8, 32), 256, 0, stream>>>(cb, wob, bo, nullptr, nullptr,
                                              out, nullptr, nullptr, nullptr, 1024);
}

// Round 4
// 214.560 us; speedup vs baseline: 11.2008x; 1.0243x over previous
//
#include <hip/hip_runtime.h>

#define SEQ 2048
#define NH 16
#define HD 64
#define DMODEL 1024

__device__ __forceinline__ unsigned int f2bf(float f) {
  // fp32 -> bf16 bits, round-to-nearest-even (finite inputs only)
  unsigned int u = __float_as_uint(f);
  return ((u + 0x7fffu + ((u >> 16) & 1u)) >> 16) & 0xffffu;
}

typedef __bf16 bf16x8 __attribute__((ext_vector_type(8)));
typedef float f32x4 __attribute__((ext_vector_type(4)));

// async global->LDS, 16B per lane; LDS dest = wave-uniform base + lane*16
__device__ __forceinline__ void gl2lds16(const unsigned short* g, unsigned short* l) {
  __builtin_amdgcn_global_load_lds(
      (const __attribute__((address_space(1))) unsigned int*)g,
      (__attribute__((address_space(3))) unsigned int*)l, 16, 0, 0);
}

// one launch casts x + all four weight matrices to bf16
__global__ __launch_bounds__(256) void cast_all_kernel(
    const float* __restrict__ x, const float* __restrict__ wq,
    const float* __restrict__ wk, const float* __restrict__ wv,
    const float* __restrict__ wo,
    unsigned short* __restrict__ xb, unsigned short* __restrict__ wqb,
    unsigned short* __restrict__ wkb, unsigned short* __restrict__ wvb,
    unsigned short* __restrict__ wob) {
  int idx = blockIdx.x * 256 + threadIdx.x;
  if (idx >= 1048576) return;
  const float* src;
  unsigned short* dst;
  int off;
  if (idx < 524288) {
    src = x; dst = xb; off = idx;
  } else {
    int t = idx - 524288;
    int w = t >> 17;
    off = t & 131071;
    src = (w == 0) ? wq : (w == 1) ? wk : (w == 2) ? wv : wo;
    dst = (w == 0) ? wqb : (w == 1) ? wkb : (w == 2) ? wvb : wob;
  }
  const float4* p = reinterpret_cast<const float4*>(src) + (size_t)off * 2;
  float4 a = p[0], b = p[1];
  uint4 o;
  o.x = f2bf(a.x) | (f2bf(a.y) << 16);
  o.y = f2bf(a.z) | (f2bf(a.w) << 16);
  o.z = f2bf(b.x) | (f2bf(b.y) << 16);
  o.w = f2bf(b.z) | (f2bf(b.w) << 16);
  reinterpret_cast<uint4*>(dst)[off] = o;
}

// 128x128-tile GEMM, BK=64, global_load_lds staging, XOR-swizzled LDS chunks:
// LDS[r][chunk c] holds global chunk c^(r&7)  -> fragment ds_read_b128 is 2-way
// bank-aliased (free) instead of 16-way conflicted.
// MODE 0: fused QKV epilogue (cols 0..1023 Q *0.125, 1024..2047 K, 2048..3071 V^T).
// MODE 1: fp32 C[M][1024] + bias0 (out projection).
template <int MODE>
__global__ __launch_bounds__(256) void gemm128(
    const unsigned short* __restrict__ A, const unsigned short* __restrict__ B,
    const float* __restrict__ bias0, const float* __restrict__ bias1,
    const float* __restrict__ bias2, float* __restrict__ Cf,
    unsigned short* __restrict__ Qo, unsigned short* __restrict__ Ko,
    unsigned short* __restrict__ Vto, int Kdim) {
  __shared__ __align__(16) unsigned short As[128 * 64];
  __shared__ __align__(16) unsigned short Bs[128 * 64];
  const int tid = threadIdx.x;
  const int wave = tid >> 6, lane = tid & 63;
  const int wm = wave >> 1, wn = wave & 1;  // 2x2 waves -> 64x64 sub-tiles
  const int fr = lane & 15, quad = lane >> 4;
  const int fx = fr & 7;  // swizzle key for fragment reads
  const int n0 = blockIdx.x * 128, m0 = blockIdx.y * 128;

  // staging: lane -> (row = lane>>3, swizzled chunk = (lane&7) ^ ((lane>>3)&7))
  const int srowg = lane >> 3;
  const int schunk = (lane & 7) ^ (srowg & 7);
  const unsigned short* Abase =
      A + (size_t)(m0 + wave * 32 + srowg) * Kdim + schunk * 8;
  const unsigned short* Bbase =
      B + (size_t)(n0 + wave * 32 + srowg) * Kdim + schunk * 8;
  unsigned short* AsW = As + (wave * 32) * 64;
  unsigned short* BsW = Bs + (wave * 32) * 64;

  f32x4 acc[4][4];
#pragma unroll
  for (int mt = 0; mt < 4; ++mt)
#pragma unroll
    for (int nt = 0; nt < 4; ++nt) acc[mt][nt] = f32x4{0.f, 0.f, 0.f, 0.f};

  for (int k0 = 0; k0 < Kdim; k0 += 64) {
#pragma unroll
    for (int t = 0; t < 4; ++t) {
      gl2lds16(Abase + (size_t)(t * 8) * Kdim + k0, AsW + t * 8 * 64);
      gl2lds16(Bbase + (size_t)(t * 8) * Kdim + k0, BsW + t * 8 * 64);
    }
    __syncthreads();  // drains vmcnt(0): staged tile visible
#pragma unroll
    for (int ks = 0; ks < 2; ++ks) {
      bf16x8 af[4], bfv[4];
#pragma unroll
      for (int mt = 0; mt < 4; ++mt)
        af[mt] = *reinterpret_cast<const bf16x8*>(
            As + (wm * 64 + mt * 16 + fr) * 64 + ((ks * 4 + quad) ^ fx) * 8);
#pragma unroll
      for (int nt = 0; nt < 4; ++nt)
        bfv[nt] = *reinterpret_cast<const bf16x8*>(
            Bs + (wn * 64 + nt * 16 + fr) * 64 + ((ks * 4 + quad) ^ fx) * 8);
#pragma unroll
      for (int mt = 0; mt < 4; ++mt)
#pragma unroll
        for (int nt = 0; nt < 4; ++nt)
          acc[mt][nt] = __builtin_amdgcn_mfma_f32_16x16x32_bf16(
              af[mt], bfv[nt], acc[mt][nt], 0, 0, 0);
    }
    __syncthreads();
  }

  // epilogue. C/D: col = lane&15, row = quad*4+reg (m89/m91-verified).
  if (MODE == 0) {
    const int seg = n0 >> 10;  // uniform per block
    const float* bp = (seg == 0) ? bias0 : (seg == 1) ? bias1 : bias2;
    const float scale = (seg == 0) ? 0.125f : 1.0f;
    unsigned short* QK = (seg == 0) ? Qo : Ko;
#pragma unroll
    for (int nt = 0; nt < 4; ++nt) {
      const int c = (n0 + wn * 64 + nt * 16 + fr) & 1023;
      const int h = c >> 6, d = c & 63;
      const float bs = bp[c];
#pragma unroll
      for (int mt = 0; mt < 4; ++mt) {
        const int mbase = m0 + wm * 64 + mt * 16 + quad * 4;
        const int b = mbase >> 11, s0 = mbase & 2047;
        if (seg < 2) {
          unsigned short* dst = QK + (((size_t)(b * NH + h)) * SEQ + s0) * HD + d;
#pragma unroll
          for (int r = 0; r < 4; ++r)
            dst[(size_t)r * HD] = (unsigned short)f2bf((acc[mt][nt][r] + bs) * scale);
        } else {  // V^T: rows contiguous in s -> ushort4
          ushort4 pk;
          pk.x = (unsigned short)f2bf(acc[mt][nt][0] + bs);
          pk.y = (unsigned short)f2bf(acc[mt][nt][1] + bs);
          pk.z = (unsigned short)f2bf(acc[mt][nt][2] + bs);
          pk.w = (unsigned short)f2bf(acc[mt][nt][3] + bs);
          *reinterpret_cast<ushort4*>(
              Vto + (((size_t)(b * NH + h)) * HD + d) * SEQ + s0) = pk;
        }
      }
    }
  } else {
#pragma unroll
    for (int nt = 0; nt < 4; ++nt) {
      const int cg = n0 + wn * 64 + nt * 16 + fr;
      const float bs = bias0[cg];
#pragma unroll
      for (int mt = 0; mt < 4; ++mt) {
        const int mbase = m0 + wm * 64 + mt * 16 + quad * 4;
#pragma unroll
        for (int r = 0; r < 4; ++r)
          Cf[(size_t)(mbase + r) * DMODEL + cg] = acc[mt][nt][r] + bs;
      }
    }
  }
}

// MFMA flash attention, 128 Q-rows per block (two q-col fragments per wave).
// S^T = K*Q^T then O^T = V^T*P^T: lane's C-col is its own Q row -> shuffle-free
// softmax state except the xor-16/32 reductions. K/V staged once per j-tile,
// used by both q-frags (halved staging + barriers per MFMA).
// Grid 512: group pairing ib = g<8 ? 15-g : g-8 balances per-CU work (66 passes).
__global__ __launch_bounds__(256) void attn_mfma_kernel(const unsigned short* __restrict__ Qg,
                                                        const unsigned short* __restrict__ Kg,
                                                        const unsigned short* __restrict__ Vtg,
                                                        const int* __restrict__ mask,
                                                        unsigned short* __restrict__ concat) {
  const int group = blockIdx.x >> 5;
  const int ib = (group < 8) ? (15 - group) : (group - 8);
  const int bh = blockIdx.x & 31;
  const int b = bh >> 4;
  const int h = bh & 15;
  const int tid = threadIdx.x;
  const int wave = tid >> 6;
  const int lane = tid & 63;
  const int quad = lane >> 4;
  const int fr = lane & 15;
  const int i0 = ib * 128;

  __shared__ unsigned short Ks[64][72];   // pitch 144 B: frag reads 2-way aliased (free)
  __shared__ unsigned short Vts[64][72];
  __shared__ unsigned short Pt[4][16][72];

  const unsigned short* Qb = Qg + ((size_t)bh * SEQ) * HD;
  const unsigned short* Kb = Kg + ((size_t)bh * SEQ) * HD;
  const unsigned short* Vtb = Vtg + ((size_t)bh * HD) * SEQ;
  const int* maskb = mask + b * SEQ;

  int irow[2];
  bf16x8 qf[2][2];
  int padi[2];
#pragma unroll
  for (int qc = 0; qc < 2; ++qc) {
    irow[qc] = i0 + qc * 64 + wave * 16 + fr;
    qf[qc][0] = *reinterpret_cast<const bf16x8*>(Qb + (size_t)irow[qc] * HD + quad * 8);
    qf[qc][1] = *reinterpret_cast<const bf16x8*>(Qb + (size_t)irow[qc] * HD + quad * 8 + 32);
    padi[qc] = maskb[irow[qc]];
  }

  f32x4 o[2][4];
#pragma unroll
  for (int qc = 0; qc < 2; ++qc)
#pragma unroll
    for (int vt = 0; vt < 4; ++vt) o[qc][vt] = f32x4{0.f, 0.f, 0.f, 0.f};
  float mrun[2] = {-1e30f, -1e30f}, lrun[2] = {0.f, 0.f};

  const int srow = tid >> 2;        // staging row 0..63
  const int spart = (tid & 3) * 2;  // uint4 part {0,2,4,6}
  const int njc = 2 * ib + 2;

  for (int jc = 0; jc < njc; ++jc) {
    const int j0 = jc * 64;
    {  // stage K tile [j][k] and V^T tile [v][j]
      const uint4* kg = reinterpret_cast<const uint4*>(Kb + (size_t)(j0 + srow) * HD);
      const uint4* vg = reinterpret_cast<const uint4*>(Vtb + (size_t)srow * SEQ + j0);
      uint4 ka = kg[spart], kc = kg[spart + 1];
      uint4 va = vg[spart], vc = vg[spart + 1];
      *reinterpret_cast<uint4*>(&Ks[srow][spart * 8]) = ka;
      *reinterpret_cast<uint4*>(&Ks[srow][spart * 8 + 8]) = kc;
      *reinterpret_cast<uint4*>(&Vts[srow][spart * 8]) = va;
      *reinterpret_cast<uint4*>(&Vts[srow][spart * 8 + 8]) = vc;
    }
    __syncthreads();

    // mask words once per tile, reused by both q-frags
    const int4* mp = reinterpret_cast<const int4*>(maskb + j0);
    int4 mvv[4];
#pragma unroll
    for (int jt = 0; jt < 4; ++jt) mvv[jt] = mp[jt * 4 + quad];

#pragma unroll
    for (int qc = 0; qc < 2; ++qc) {
      if (qc == 0 && jc == 2 * ib + 1) continue;  // fully causal-masked pass
      const bool diag = (jc == 2 * ib + qc);
      const int ir = irow[qc];

      // S^T strip: C[m=j][n=i=fr]
      f32x4 st[4];
#pragma unroll
      for (int jt = 0; jt < 4; ++jt) {
        st[jt] = f32x4{0.f, 0.f, 0.f, 0.f};
        bf16x8 ka0 = *reinterpret_cast<const bf16x8*>(&Ks[jt * 16 + fr][quad * 8]);
        bf16x8 ka1 = *reinterpret_cast<const bf16x8*>(&Ks[jt * 16 + fr][quad * 8 + 32]);
        st[jt] = __builtin_amdgcn_mfma_f32_16x16x32_bf16(ka0, qf[qc][0], st[jt], 0, 0, 0);
        st[jt] = __builtin_amdgcn_mfma_f32_16x16x32_bf16(ka1, qf[qc][1], st[jt], 0, 0, 0);
      }

#pragma unroll
      for (int jt = 0; jt < 4; ++jt) {
        const int4 mv = mvv[jt];
        const int jb = j0 + jt * 16 + quad * 4;
        if (mv.x == 0 || (diag && jb + 0 > ir)) st[jt][0] = -1e30f;
        if (mv.y == 0 || (diag && jb + 1 > ir)) st[jt][1] = -1e30f;
        if (mv.z == 0 || (diag && jb + 2 > ir)) st[jt][2] = -1e30f;
        if (mv.w == 0 || (diag && jb + 3 > ir)) st[jt][3] = -1e30f;
      }

      // online softmax for row i=fr (16 of 64 j's per lane; quads merged via xor)
      float tmax = -1e30f;
#pragma unroll
      for (int jt = 0; jt < 4; ++jt)
#pragma unroll
        for (int r = 0; r < 4; ++r) tmax = fmaxf(tmax, st[jt][r]);
      tmax = fmaxf(tmax, __shfl_xor(tmax, 16));
      tmax = fmaxf(tmax, __shfl_xor(tmax, 32));
      float mnew = fmaxf(fmaxf(mrun[qc], tmax), -1e20f);  // all-masked tile -> p=0
      const float corr = __expf(mrun[qc] - mnew);
      float p[16];
      float lloc = 0.f;
#pragma unroll
      for (int jt = 0; jt < 4; ++jt)
#pragma unroll
        for (int r = 0; r < 4; ++r) {
          float pv = __expf(st[jt][r] - mnew);
          p[jt * 4 + r] = pv;
          lloc += pv;
        }
      lloc += __shfl_xor(lloc, 16);
      lloc += __shfl_xor(lloc, 32);
      lrun[qc] = lrun[qc] * corr + lloc;
      mrun[qc] = mnew;

      // P (bf16) -> per-wave LDS strip [i][j] (wave-private, lgkmcnt-ordered)
#pragma unroll
      for (int jt = 0; jt < 4; ++jt) {
        ushort4 pk;
        pk.x = (unsigned short)f2bf(p[jt * 4 + 0]);
        pk.y = (unsigned short)f2bf(p[jt * 4 + 1]);
        pk.z = (unsigned short)f2bf(p[jt * 4 + 2]);
        pk.w = (unsigned short)f2bf(p[jt * 4 + 3]);
        *reinterpret_cast<ushort4*>(&Pt[wave][fr][jt * 16 + quad * 4]) = pk;
      }

      // O^T rescale: lane's col is its own Q row -> no shuffles
#pragma unroll
      for (int vt = 0; vt < 4; ++vt) {
        o[qc][vt][0] *= corr; o[qc][vt][1] *= corr;
        o[qc][vt][2] *= corr; o[qc][vt][3] *= corr;
      }

      // O^T += V^T * P^T
      bf16x8 pa0 = *reinterpret_cast<const bf16x8*>(&Pt[wave][fr][quad * 8]);
      bf16x8 pa1 = *reinterpret_cast<const bf16x8*>(&Pt[wave][fr][quad * 8 + 32]);
#pragma unroll
      for (int vt = 0; vt < 4; ++vt) {
        bf16x8 vb0 = *reinterpret_cast<const bf16x8*>(&Vts[vt * 16 + fr][quad * 8]);
        bf16x8 vb1 = *reinterpret_cast<const bf16x8*>(&Vts[vt * 16 + fr][quad * 8 + 32]);
        o[qc][vt] = __builtin_amdgcn_mfma_f32_16x16x32_bf16(vb0, pa0, o[qc][vt], 0, 0, 0);
        o[qc][vt] = __builtin_amdgcn_mfma_f32_16x16x32_bf16(vb1, pa1, o[qc][vt], 0, 0, 0);
      }
    }
    __syncthreads();  // protect Ks/Vts before next stage
  }

  // epilogue: O^T[v][i=fr] / l_i -> concat bf16 [b,s,h*64]
#pragma unroll
  for (int qc = 0; qc < 2; ++qc) {
    const float inv = (padi[qc] != 0 && lrun[qc] > 0.f) ? 1.f / lrun[qc] : 0.f;
    unsigned short* orow = concat + ((size_t)(b * SEQ + irow[qc])) * DMODEL + h * HD;
#pragma unroll
    for (int vt = 0; vt < 4; ++vt) {
      ushort4 pk;
      pk.x = (unsigned short)f2bf(o[qc][vt][0] * inv);
      pk.y = (unsigned short)f2bf(o[qc][vt][1] * inv);
      pk.z = (unsigned short)f2bf(o[qc][vt][2] * inv);
      pk.w = (unsigned short)f2bf(o[qc][vt][3] * inv);
      *reinterpret_cast<ushort4*>(orow + vt * 16 + quad * 4) = pk;
    }
  }
}

extern "C" void kernel_launch(void* const* d_in, const int* in_sizes, int n_in,
                              void* d_out, int out_size, void* d_ws, size_t ws_size,
                              hipStream_t stream) {
  (void)in_sizes; (void)n_in; (void)out_size;
  const float* x  = (const float*)d_in[0];
  const int* mask = (const int*)d_in[1];
  const float* Wq = (const float*)d_in[2];
  const float* bq = (const float*)d_in[3];
  const float* Wk = (const float*)d_in[4];
  const float* bk = (const float*)d_in[5];
  const float* Wv = (const float*)d_in[6];
  const float* bv = (const float*)d_in[7];
  const float* Wo = (const float*)d_in[8];
  const float* bo = (const float*)d_in[9];
  float* out = (float*)d_out;

  char* ws = (char*)d_ws;
  if (ws_size < (48ull << 20)) return;
  unsigned short* xb  = (unsigned short*)(ws);                 // 8 MB x bf16 [4096][1024]
  unsigned short* wqb = (unsigned short*)(ws + (8ull  << 20)); // wq|wk|wv contiguous ->
  unsigned short* wkb = (unsigned short*)(ws + (10ull << 20)); //   [3072][1024] B matrix
  unsigned short* wvb = (unsigned short*)(ws + (12ull << 20));
  unsigned short* wob = (unsigned short*)(ws + (14ull << 20));
  unsigned short* Qb  = (unsigned short*)(ws + (16ull << 20)); // 8 MB [b,h,s,64] (x0.125)
  unsigned short* Kb  = (unsigned short*)(ws + (24ull << 20)); // 8 MB [b,h,s,64]
  unsigned short* Vtb = (unsigned short*)(ws + (32ull << 20)); // 8 MB [b,h,64,s]
  unsigned short* cb  = (unsigned short*)(ws + (40ull << 20)); // 8 MB concat bf16

  cast_all_kernel<<<4096, 256, 0, stream>>>(x, Wq, Wk, Wv, Wo, xb, wqb, wkb, wvb, wob);

  // fused QKV projection: B = [wq; wk; wv] = [3072][1024]
  gemm128<0><<<dim3(24, 32), 256, 0, stream>>>(xb, wqb, bq, bk, bv,
                                               nullptr, Qb, Kb, Vtb, 1024);

  attn_mfma_kernel<<<512, 256, 0, stream>>>(Qb, Kb, Vtb, mask, cb);

  gemm128<1><<<dim3(8, 32), 256, 0, stream>>>(cb, wob, bo, nullptr, nullptr,
                                              out, nullptr, nullptr, nullptr, 1024);
}

// Round 5
// 200.631 us; speedup vs baseline: 11.9784x; 1.0694x over previous
//
#include <hip/hip_runtime.h>

#define SEQ 2048
#define NH 16
#define HD 64
#define DMODEL 1024

__device__ __forceinline__ unsigned int f2bf(float f) {
  // fp32 -> bf16 bits, round-to-nearest-even (finite inputs only)
  unsigned int u = __float_as_uint(f);
  return ((u + 0x7fffu + ((u >> 16) & 1u)) >> 16) & 0xffffu;
}

// packed fp32x2 -> bf16x2 via hw v_cvt (RNE on gfx950)
__device__ __forceinline__ unsigned int pk2bf(float a, float b) {
  unsigned short ua = __builtin_bit_cast(unsigned short, (__bf16)a);
  unsigned short ub = __builtin_bit_cast(unsigned short, (__bf16)b);
  return (unsigned int)ua | ((unsigned int)ub << 16);
}

typedef __bf16 bf16x8 __attribute__((ext_vector_type(8)));
typedef float f32x4 __attribute__((ext_vector_type(4)));

// async global->LDS, 16B per lane; LDS dest = wave-uniform base + lane*16
__device__ __forceinline__ void gl2lds16(const unsigned short* g, unsigned short* l) {
  __builtin_amdgcn_global_load_lds(
      (const __attribute__((address_space(1))) unsigned int*)g,
      (__attribute__((address_space(3))) unsigned int*)l, 16, 0, 0);
}

// one launch casts x + all four weight matrices to bf16
__global__ __launch_bounds__(256) void cast_all_kernel(
    const float* __restrict__ x, const float* __restrict__ wq,
    const float* __restrict__ wk, const float* __restrict__ wv,
    const float* __restrict__ wo,
    unsigned short* __restrict__ xb, unsigned short* __restrict__ wqb,
    unsigned short* __restrict__ wkb, unsigned short* __restrict__ wvb,
    unsigned short* __restrict__ wob) {
  int idx = blockIdx.x * 256 + threadIdx.x;
  if (idx >= 1048576) return;
  const float* src;
  unsigned short* dst;
  int off;
  if (idx < 524288) {
    src = x; dst = xb; off = idx;
  } else {
    int t = idx - 524288;
    int w = t >> 17;
    off = t & 131071;
    src = (w == 0) ? wq : (w == 1) ? wk : (w == 2) ? wv : wo;
    dst = (w == 0) ? wqb : (w == 1) ? wkb : (w == 2) ? wvb : wob;
  }
  const float4* p = reinterpret_cast<const float4*>(src) + (size_t)off * 2;
  float4 a = p[0], b = p[1];
  uint4 o;
  o.x = f2bf(a.x) | (f2bf(a.y) << 16);
  o.y = f2bf(a.z) | (f2bf(a.w) << 16);
  o.z = f2bf(b.x) | (f2bf(b.y) << 16);
  o.w = f2bf(b.z) | (f2bf(b.w) << 16);
  reinterpret_cast<uint4*>(dst)[idx == off ? off : off] = o;  // dst[off]
}

// 128x128-tile GEMM, BK=64, global_load_lds staging, XOR-swizzled LDS chunks.
// MODE 0: fused QKV epilogue (cols 0..1023 Q *qscale, 1024..2047 K, 2048..3071 V^T).
// MODE 1: fp32 C[M][1024] + bias0 (out projection).
template <int MODE>
__global__ __launch_bounds__(256) void gemm128(
    const unsigned short* __restrict__ A, const unsigned short* __restrict__ B,
    const float* __restrict__ bias0, const float* __restrict__ bias1,
    const float* __restrict__ bias2, float* __restrict__ Cf,
    unsigned short* __restrict__ Qo, unsigned short* __restrict__ Ko,
    unsigned short* __restrict__ Vto, int Kdim) {
  __shared__ __align__(16) unsigned short As[128 * 64];
  __shared__ __align__(16) unsigned short Bs[128 * 64];
  const int tid = threadIdx.x;
  const int wave = tid >> 6, lane = tid & 63;
  const int wm = wave >> 1, wn = wave & 1;  // 2x2 waves -> 64x64 sub-tiles
  const int fr = lane & 15, quad = lane >> 4;
  const int fx = fr & 7;  // swizzle key for fragment reads
  const int n0 = blockIdx.x * 128, m0 = blockIdx.y * 128;

  // staging: lane -> (row = lane>>3, swizzled chunk = (lane&7) ^ ((lane>>3)&7))
  const int srowg = lane >> 3;
  const int schunk = (lane & 7) ^ (srowg & 7);
  const unsigned short* Abase =
      A + (size_t)(m0 + wave * 32 + srowg) * Kdim + schunk * 8;
  const unsigned short* Bbase =
      B + (size_t)(n0 + wave * 32 + srowg) * Kdim + schunk * 8;
  unsigned short* AsW = As + (wave * 32) * 64;
  unsigned short* BsW = Bs + (wave * 32) * 64;

  f32x4 acc[4][4];
#pragma unroll
  for (int mt = 0; mt < 4; ++mt)
#pragma unroll
    for (int nt = 0; nt < 4; ++nt) acc[mt][nt] = f32x4{0.f, 0.f, 0.f, 0.f};

  for (int k0 = 0; k0 < Kdim; k0 += 64) {
#pragma unroll
    for (int t = 0; t < 4; ++t) {
      gl2lds16(Abase + (size_t)(t * 8) * Kdim + k0, AsW + t * 8 * 64);
      gl2lds16(Bbase + (size_t)(t * 8) * Kdim + k0, BsW + t * 8 * 64);
    }
    __syncthreads();  // drains vmcnt(0): staged tile visible
#pragma unroll
    for (int ks = 0; ks < 2; ++ks) {
      bf16x8 af[4], bfv[4];
#pragma unroll
      for (int mt = 0; mt < 4; ++mt)
        af[mt] = *reinterpret_cast<const bf16x8*>(
            As + (wm * 64 + mt * 16 + fr) * 64 + ((ks * 4 + quad) ^ fx) * 8);
#pragma unroll
      for (int nt = 0; nt < 4; ++nt)
        bfv[nt] = *reinterpret_cast<const bf16x8*>(
            Bs + (wn * 64 + nt * 16 + fr) * 64 + ((ks * 4 + quad) ^ fx) * 8);
#pragma unroll
      for (int mt = 0; mt < 4; ++mt)
#pragma unroll
        for (int nt = 0; nt < 4; ++nt)
          acc[mt][nt] = __builtin_amdgcn_mfma_f32_16x16x32_bf16(
              af[mt], bfv[nt], acc[mt][nt], 0, 0, 0);
    }
    __syncthreads();
  }

  // epilogue. C/D: col = lane&15, row = quad*4+reg (m89/m91-verified).
  if (MODE == 0) {
    const int seg = n0 >> 10;  // uniform per block
    const float* bp = (seg == 0) ? bias0 : (seg == 1) ? bias1 : bias2;
    // Q pre-scaled by (1/sqrt(64)) * log2(e): attention works in exp2 domain
    const float scale = (seg == 0) ? 0.1803368809f : 1.0f;
    unsigned short* QK = (seg == 0) ? Qo : Ko;
#pragma unroll
    for (int nt = 0; nt < 4; ++nt) {
      const int c = (n0 + wn * 64 + nt * 16 + fr) & 1023;
      const int h = c >> 6, d = c & 63;
      const float bs = bp[c];
#pragma unroll
      for (int mt = 0; mt < 4; ++mt) {
        const int mbase = m0 + wm * 64 + mt * 16 + quad * 4;
        const int b = mbase >> 11, s0 = mbase & 2047;
        if (seg < 2) {
          unsigned short* dst = QK + (((size_t)(b * NH + h)) * SEQ + s0) * HD + d;
#pragma unroll
          for (int r = 0; r < 4; ++r)
            dst[(size_t)r * HD] = (unsigned short)f2bf((acc[mt][nt][r] + bs) * scale);
        } else {  // V^T: rows contiguous in s -> ushort4
          uint2 pk;
          pk.x = pk2bf(acc[mt][nt][0] + bs, acc[mt][nt][1] + bs);
          pk.y = pk2bf(acc[mt][nt][2] + bs, acc[mt][nt][3] + bs);
          *reinterpret_cast<uint2*>(
              Vto + (((size_t)(b * NH + h)) * HD + d) * SEQ + s0) = pk;
        }
      }
    }
  } else {
#pragma unroll
    for (int nt = 0; nt < 4; ++nt) {
      const int cg = n0 + wn * 64 + nt * 16 + fr;
      const float bs = bias0[cg];
#pragma unroll
      for (int mt = 0; mt < 4; ++mt) {
        const int mbase = m0 + wm * 64 + mt * 16 + quad * 4;
#pragma unroll
        for (int r = 0; r < 4; ++r)
          Cf[(size_t)(mbase + r) * DMODEL + cg] = acc[mt][nt][r] + bs;
      }
    }
  }
}

// MFMA flash attention, exp2 domain (Q pre-scaled by 0.125*log2e).
// 512 equal-work blocks: block (g, bh), g in [0,16), handles i-tiles {31-g, g}
// in ONE j-loop (K/V staged once, shared). Every block does exactly 33 passes.
// S^T = K*Q^T then O^T = V^T*P^T: lane's C-col is its own Q row (shuffle-free
// state except xor-16/32 reductions). Pad-mask hoisted to a per-tile bad-bitmap.
__global__ __launch_bounds__(256, 3) void attn_mfma_kernel(
    const unsigned short* __restrict__ Qg, const unsigned short* __restrict__ Kg,
    const unsigned short* __restrict__ Vtg, const int* __restrict__ mask,
    unsigned short* __restrict__ concat) {
  const int g = blockIdx.x >> 5;        // 0..15
  const int bh = blockIdx.x & 31;
  const int b = bh >> 4;
  const int h = bh & 15;
  const int tid = threadIdx.x;
  const int wave = tid >> 6;
  const int lane = tid & 63;
  const int quad = lane >> 4;
  const int fr = lane & 15;
  const int ibA = 31 - g, ibB = g;      // two 64-row i-tiles

  __shared__ unsigned short Ks[64][72];   // pitch 144 B
  __shared__ unsigned short Vts[64][72];
  __shared__ unsigned short Pt[2][4][16][72];
  __shared__ unsigned int tilebad;

  const unsigned short* Qb = Qg + ((size_t)bh * SEQ) * HD;
  const unsigned short* Kb = Kg + ((size_t)bh * SEQ) * HD;
  const unsigned short* Vtb = Vtg + ((size_t)bh * HD) * SEQ;
  const int* maskb = mask + b * SEQ;

  // per-tile pad-mask "bad" bitmap (bit jc set if tile jc has any zero)
  if (tid == 0) tilebad = 0;
  __syncthreads();
  {
    const int4* mp4 = reinterpret_cast<const int4*>(maskb);
    int4 a = mp4[tid * 2], c = mp4[tid * 2 + 1];
    if (!(a.x && a.y && a.z && a.w && c.x && c.y && c.z && c.w))
      atomicOr(&tilebad, 1u << (tid >> 3));
  }
  __syncthreads();
  const unsigned int tbad = tilebad;

  const int irA = ibA * 64 + wave * 16 + fr;
  const int irB = ibB * 64 + wave * 16 + fr;
  const bf16x8 qA0 = *reinterpret_cast<const bf16x8*>(Qb + (size_t)irA * HD + quad * 8);
  const bf16x8 qA1 = *reinterpret_cast<const bf16x8*>(Qb + (size_t)irA * HD + quad * 8 + 32);
  const bf16x8 qB0 = *reinterpret_cast<const bf16x8*>(Qb + (size_t)irB * HD + quad * 8);
  const bf16x8 qB1 = *reinterpret_cast<const bf16x8*>(Qb + (size_t)irB * HD + quad * 8 + 32);
  const int padA = maskb[irA], padB = maskb[irB];

  f32x4 oA[4], oB[4];
#pragma unroll
  for (int vt = 0; vt < 4; ++vt) { oA[vt] = f32x4{0,0,0,0}; oB[vt] = f32x4{0,0,0,0}; }
  // init -1e20 (not -1e30): all-masked tiles then give exp2(-1e30+1e20)=0 safely
  float mA = -1e20f, lA = 0.f, mB = -1e20f, lB = 0.f;

  const int srow = tid >> 2;        // staging row 0..63
  const int spart = (tid & 3) * 2;  // uint4 part {0,2,4,6}

  for (int jc = 0; jc <= ibA; ++jc) {
    const int j0 = jc * 64;
    {  // stage K tile [j][k] and V^T tile [v][j]
      const uint4* kg = reinterpret_cast<const uint4*>(Kb + (size_t)(j0 + srow) * HD);
      const uint4* vg = reinterpret_cast<const uint4*>(Vtb + (size_t)srow * SEQ + j0);
      uint4 ka = kg[spart], kc = kg[spart + 1];
      uint4 va = vg[spart], vc = vg[spart + 1];
      *reinterpret_cast<uint4*>(&Ks[srow][spart * 8]) = ka;
      *reinterpret_cast<uint4*>(&Ks[srow][spart * 8 + 8]) = kc;
      *reinterpret_cast<uint4*>(&Vts[srow][spart * 8]) = va;
      *reinterpret_cast<uint4*>(&Vts[srow][spart * 8 + 8]) = vc;
    }
    __syncthreads();

    const bool doB = (jc <= ibB);
    const bool diagA = (jc == ibA), diagB = (jc == ibB);
    const bool tb = (tbad >> jc) & 1u;

    // S^T strips for both i-tiles, sharing the Ks fragment reads
    f32x4 stA[4], stB[4];
#pragma unroll
    for (int jt = 0; jt < 4; ++jt) {
      bf16x8 ka0 = *reinterpret_cast<const bf16x8*>(&Ks[jt * 16 + fr][quad * 8]);
      bf16x8 ka1 = *reinterpret_cast<const bf16x8*>(&Ks[jt * 16 + fr][quad * 8 + 32]);
      stA[jt] = f32x4{0,0,0,0};
      stA[jt] = __builtin_amdgcn_mfma_f32_16x16x32_bf16(ka0, qA0, stA[jt], 0, 0, 0);
      stA[jt] = __builtin_amdgcn_mfma_f32_16x16x32_bf16(ka1, qA1, stA[jt], 0, 0, 0);
      if (doB) {
        stB[jt] = f32x4{0,0,0,0};
        stB[jt] = __builtin_amdgcn_mfma_f32_16x16x32_bf16(ka0, qB0, stB[jt], 0, 0, 0);
        stB[jt] = __builtin_amdgcn_mfma_f32_16x16x32_bf16(ka1, qB1, stB[jt], 0, 0, 0);
      }
    }

    if (tb) {  // rare: per-element pad-col mask
      const int4* mp = reinterpret_cast<const int4*>(maskb + j0);
#pragma unroll
      for (int jt = 0; jt < 4; ++jt) {
        const int4 mv = mp[jt * 4 + quad];
        if (mv.x == 0) { stA[jt][0] = -1e30f; if (doB) stB[jt][0] = -1e30f; }
        if (mv.y == 0) { stA[jt][1] = -1e30f; if (doB) stB[jt][1] = -1e30f; }
        if (mv.z == 0) { stA[jt][2] = -1e30f; if (doB) stB[jt][2] = -1e30f; }
        if (mv.w == 0) { stA[jt][3] = -1e30f; if (doB) stB[jt][3] = -1e30f; }
      }
    }
    if (diagA) {
#pragma unroll
      for (int jt = 0; jt < 4; ++jt) {
        const int jb = j0 + jt * 16 + quad * 4;
#pragma unroll
        for (int r = 0; r < 4; ++r)
          if (jb + r > irA) stA[jt][r] = -1e30f;
      }
    }
    if (doB && diagB) {
#pragma unroll
      for (int jt = 0; jt < 4; ++jt) {
        const int jb = j0 + jt * 16 + quad * 4;
#pragma unroll
        for (int r = 0; r < 4; ++r)
          if (jb + r > irB) stB[jt][r] = -1e30f;
      }
    }

    // ---- softmax + Pt pack, tile A ----
    {
      float tmax = -1e30f;
#pragma unroll
      for (int jt = 0; jt < 4; ++jt)
#pragma unroll
        for (int r = 0; r < 4; ++r) tmax = fmaxf(tmax, stA[jt][r]);
      tmax = fmaxf(tmax, __shfl_xor(tmax, 16));
      tmax = fmaxf(tmax, __shfl_xor(tmax, 32));
      const bool upd = __ballot(tmax > mA) != 0ull;  // wave-uniform
      float corr = 1.f;
      if (upd) { const float mn = fmaxf(mA, tmax); corr = __builtin_amdgcn_exp2f(mA - mn); mA = mn; }
      float lloc = 0.f;
#pragma unroll
      for (int jt = 0; jt < 4; ++jt) {
        float p0 = __builtin_amdgcn_exp2f(stA[jt][0] - mA);
        float p1 = __builtin_amdgcn_exp2f(stA[jt][1] - mA);
        float p2 = __builtin_amdgcn_exp2f(stA[jt][2] - mA);
        float p3 = __builtin_amdgcn_exp2f(stA[jt][3] - mA);
        lloc += (p0 + p1) + (p2 + p3);
        uint2 pk; pk.x = pk2bf(p0, p1); pk.y = pk2bf(p2, p3);
        *reinterpret_cast<uint2*>(&Pt[0][wave][fr][jt * 16 + quad * 4]) = pk;
      }
      lloc += __shfl_xor(lloc, 16);
      lloc += __shfl_xor(lloc, 32);
      if (upd) {
        lA = lA * corr + lloc;
#pragma unroll
        for (int vt = 0; vt < 4; ++vt) {
          oA[vt][0] *= corr; oA[vt][1] *= corr; oA[vt][2] *= corr; oA[vt][3] *= corr;
        }
      } else lA += lloc;
    }
    // ---- softmax + Pt pack, tile B ----
    if (doB) {
      float tmax = -1e30f;
#pragma unroll
      for (int jt = 0; jt < 4; ++jt)
#pragma unroll
        for (int r = 0; r < 4; ++r) tmax = fmaxf(tmax, stB[jt][r]);
      tmax = fmaxf(tmax, __shfl_xor(tmax, 16));
      tmax = fmaxf(tmax, __shfl_xor(tmax, 32));
      const bool upd = __ballot(tmax > mB) != 0ull;
      float corr = 1.f;
      if (upd) { const float mn = fmaxf(mB, tmax); corr = __builtin_amdgcn_exp2f(mB - mn); mB = mn; }
      float lloc = 0.f;
#pragma unroll
      for (int jt = 0; jt < 4; ++jt) {
        float p0 = __builtin_amdgcn_exp2f(stB[jt][0] - mB);
        float p1 = __builtin_amdgcn_exp2f(stB[jt][1] - mB);
        float p2 = __builtin_amdgcn_exp2f(stB[jt][2] - mB);
        float p3 = __builtin_amdgcn_exp2f(stB[jt][3] - mB);
        lloc += (p0 + p1) + (p2 + p3);
        uint2 pk; pk.x = pk2bf(p0, p1); pk.y = pk2bf(p2, p3);
        *reinterpret_cast<uint2*>(&Pt[1][wave][fr][jt * 16 + quad * 4]) = pk;
      }
      lloc += __shfl_xor(lloc, 16);
      lloc += __shfl_xor(lloc, 32);
      if (upd) {
        lB = lB * corr + lloc;
#pragma unroll
        for (int vt = 0; vt < 4; ++vt) {
          oB[vt][0] *= corr; oB[vt][1] *= corr; oB[vt][2] *= corr; oB[vt][3] *= corr;
        }
      } else lB += lloc;
    }

    // ---- O^T += V^T * P^T, sharing Vts fragment reads ----
    bf16x8 paA0 = *reinterpret_cast<const bf16x8*>(&Pt[0][wave][fr][quad * 8]);
    bf16x8 paA1 = *reinterpret_cast<const bf16x8*>(&Pt[0][wave][fr][quad * 8 + 32]);
    bf16x8 paB0, paB1;
    if (doB) {
      paB0 = *reinterpret_cast<const bf16x8*>(&Pt[1][wave][fr][quad * 8]);
      paB1 = *reinterpret_cast<const bf16x8*>(&Pt[1][wave][fr][quad * 8 + 32]);
    }
#pragma unroll
    for (int vt = 0; vt < 4; ++vt) {
      bf16x8 vb0 = *reinterpret_cast<const bf16x8*>(&Vts[vt * 16 + fr][quad * 8]);
      bf16x8 vb1 = *reinterpret_cast<const bf16x8*>(&Vts[vt * 16 + fr][quad * 8 + 32]);
      oA[vt] = __builtin_amdgcn_mfma_f32_16x16x32_bf16(vb0, paA0, oA[vt], 0, 0, 0);
      oA[vt] = __builtin_amdgcn_mfma_f32_16x16x32_bf16(vb1, paA1, oA[vt], 0, 0, 0);
      if (doB) {
        oB[vt] = __builtin_amdgcn_mfma_f32_16x16x32_bf16(vb0, paB0, oB[vt], 0, 0, 0);
        oB[vt] = __builtin_amdgcn_mfma_f32_16x16x32_bf16(vb1, paB1, oB[vt], 0, 0, 0);
      }
    }
    __syncthreads();  // protect Ks/Vts before next stage
  }

  // epilogue: O^T[v][i=fr] / l_i -> concat bf16 [b,s,h*64]
  {
    const float inv = (padA != 0 && lA > 0.f) ? 1.f / lA : 0.f;
    unsigned short* orow = concat + ((size_t)(b * SEQ + irA)) * DMODEL + h * HD;
#pragma unroll
    for (int vt = 0; vt < 4; ++vt) {
      uint2 pk;
      pk.x = pk2bf(oA[vt][0] * inv, oA[vt][1] * inv);
      pk.y = pk2bf(oA[vt][2] * inv, oA[vt][3] * inv);
      *reinterpret_cast<uint2*>(orow + vt * 16 + quad * 4) = pk;
    }
  }
  {
    const float inv = (padB != 0 && lB > 0.f) ? 1.f / lB : 0.f;
    unsigned short* orow = concat + ((size_t)(b * SEQ + irB)) * DMODEL + h * HD;
#pragma unroll
    for (int vt = 0; vt < 4; ++vt) {
      uint2 pk;
      pk.x = pk2bf(oB[vt][0] * inv, oB[vt][1] * inv);
      pk.y = pk2bf(oB[vt][2] * inv, oB[vt][3] * inv);
      *reinterpret_cast<uint2*>(orow + vt * 16 + quad * 4) = pk;
    }
  }
}

extern "C" void kernel_launch(void* const* d_in, const int* in_sizes, int n_in,
                              void* d_out, int out_size, void* d_ws, size_t ws_size,
                              hipStream_t stream) {
  (void)in_sizes; (void)n_in; (void)out_size;
  const float* x  = (const float*)d_in[0];
  const int* mask = (const int*)d_in[1];
  const float* Wq = (const float*)d_in[2];
  const float* bq = (const float*)d_in[3];
  const float* Wk = (const float*)d_in[4];
  const float* bk = (const float*)d_in[5];
  const float* Wv = (const float*)d_in[6];
  const float* bv = (const float*)d_in[7];
  const float* Wo = (const float*)d_in[8];
  const float* bo = (const float*)d_in[9];
  float* out = (float*)d_out;

  char* ws = (char*)d_ws;
  if (ws_size < (48ull << 20)) return;
  unsigned short* xb  = (unsigned short*)(ws);                 // 8 MB x bf16 [4096][1024]
  unsigned short* wqb = (unsigned short*)(ws + (8ull  << 20)); // wq|wk|wv contiguous ->
  unsigned short* wkb = (unsigned short*)(ws + (10ull << 20)); //   [3072][1024] B matrix
  unsigned short* wvb = (unsigned short*)(ws + (12ull << 20));
  unsigned short* wob = (unsigned short*)(ws + (14ull << 20));
  unsigned short* Qb  = (unsigned short*)(ws + (16ull << 20)); // 8 MB [b,h,s,64] (xscale)
  unsigned short* Kb  = (unsigned short*)(ws + (24ull << 20)); // 8 MB [b,h,s,64]
  unsigned short* Vtb = (unsigned short*)(ws + (32ull << 20)); // 8 MB [b,h,64,s]
  unsigned short* cb  = (unsigned short*)(ws + (40ull << 20)); // 8 MB concat bf16

  cast_all_kernel<<<4096, 256, 0, stream>>>(x, Wq, Wk, Wv, Wo, xb, wqb, wkb, wvb, wob);

  // fused QKV projection: B = [wq; wk; wv] = [3072][1024]
  gemm128<0><<<dim3(24, 32), 256, 0, stream>>>(xb, wqb, bq, bk, bv,
                                               nullptr, Qb, Kb, Vtb, 1024);

  attn_mfma_kernel<<<512, 256, 0, stream>>>(Qb, Kb, Vtb, mask, cb);

  gemm128<1><<<dim3(8, 32), 256, 0, stream>>>(cb, wob, bo, nullptr, nullptr,
                                              out, nullptr, nullptr, nullptr, 1024);
}